// Round 1
// baseline (679.846 us; speedup 1.0000x reference)
//
#include <hip/hip_runtime.h>
#include <hip/hip_bf16.h>
#include <cstdint>
#include <cstddef>

#define NNODES 50000

// ---------------- CSR build ----------------

__global__ void k_deg_init(int* __restrict__ deg, int n) {
  int i = blockIdx.x * 256 + threadIdx.x;
  if (i < n) deg[i] = 1;  // self-loop
}

__global__ void k_deg_count(const int* __restrict__ ei, int* __restrict__ deg, int E) {
  int e = blockIdx.x * 256 + threadIdx.x;
  if (e < E) atomicAdd(&deg[ei[E + e]], 1);
}

__global__ void k_scan(const int* __restrict__ deg, int* __restrict__ offs, int n) {
  __shared__ int sums[256];
  int t = threadIdx.x;
  const int CH = (n + 255) / 256;
  int c0 = t * CH, c1 = min(n, c0 + CH);
  int s = 0;
  for (int i = c0; i < c1; ++i) s += deg[i];
  sums[t] = s;
  __syncthreads();
  for (int off = 1; off < 256; off <<= 1) {
    int v = (t >= off) ? sums[t - off] : 0;
    __syncthreads();
    sums[t] += v;
    __syncthreads();
  }
  int run = (t == 0) ? 0 : sums[t - 1];
  if (t == 0) offs[0] = 0;
  for (int i = c0; i < c1; ++i) { run += deg[i]; offs[i + 1] = run; }
}

__global__ void k_selfloop(const int* __restrict__ offs, int* __restrict__ cursor,
                           int* __restrict__ srt, int n) {
  int i = blockIdx.x * 256 + threadIdx.x;
  if (i < n) { cursor[i] = 1; srt[offs[i]] = i; }
}

__global__ void k_scatter(const int* __restrict__ ei, const int* __restrict__ offs,
                          int* __restrict__ cursor, int* __restrict__ srt, int E) {
  int e = blockIdx.x * 256 + threadIdx.x;
  if (e < E) {
    int s = ei[e], d = ei[E + e];
    int pos = offs[d] + atomicAdd(&cursor[d], 1);
    srt[pos] = s;
  }
}

// ---------------- fused GEMM: h = x@W, xR = x@R ----------------

template<int KDIM, int DO>
__global__ __launch_bounds__(256) void gemm_fused(
    const float* __restrict__ x, const float* __restrict__ W,
    const float* __restrict__ R, float* __restrict__ h, float* __restrict__ xR) {
  constexpr int DOW = 2 * DO;
  constexpr int TX  = (DOW >= 192) ? 16 : 8;
  constexpr int NTY = 256 / TX;
  constexpr int ROWS = NTY * 4;      // 64 or 128
  constexpr int KC = 32;
  constexpr int XP = ROWS + 4;
  constexpr int WP = DOW + 4;
  __shared__ float xt[KC * XP];
  __shared__ float wl[KC * WP];
  const int tid = threadIdx.x;
  const int tx = tid % TX, ty = tid / TX;
  const int row0 = blockIdx.x * ROWS;

  float acc[4][12];
  #pragma unroll
  for (int r = 0; r < 4; ++r)
    #pragma unroll
    for (int c = 0; c < 12; ++c) acc[r][c] = 0.f;

  for (int k0 = 0; k0 < KDIM; k0 += KC) {
    __syncthreads();
    constexpr int NX4 = ROWS * KC / 4;  // multiple of 256
    for (int id = tid; id < NX4; id += 256) {
      int r = id / (KC / 4), k4 = id % (KC / 4);
      int gr = row0 + r;
      float4 v = make_float4(0.f, 0.f, 0.f, 0.f);
      if (gr < NNODES) v = *(const float4*)&x[(size_t)gr * KDIM + k0 + k4 * 4];
      int kk = k4 * 4;
      xt[(kk + 0) * XP + r] = v.x;
      xt[(kk + 1) * XP + r] = v.y;
      xt[(kk + 2) * XP + r] = v.z;
      xt[(kk + 3) * XP + r] = v.w;
    }
    constexpr int NW4 = DOW * KC / 4;  // multiple of 256
    for (int id = tid; id < NW4; id += 256) {
      int k = id / (DOW / 4), c = (id % (DOW / 4)) * 4;
      const float* sp = (c < DO) ? &W[(size_t)(k0 + k) * DO + c]
                                 : &R[(size_t)(k0 + k) * DO + (c - DO)];
      *(float4*)&wl[k * WP + c] = *(const float4*)sp;
    }
    __syncthreads();
    #pragma unroll 8
    for (int kk = 0; kk < KC; ++kk) {
      float4 xv = *(const float4*)&xt[kk * XP + ty * 4];
      float4 w0 = *(const float4*)&wl[kk * WP + tx * 12 + 0];
      float4 w1 = *(const float4*)&wl[kk * WP + tx * 12 + 4];
      float4 w2 = *(const float4*)&wl[kk * WP + tx * 12 + 8];
      float xr[4] = {xv.x, xv.y, xv.z, xv.w};
      float wc[12] = {w0.x, w0.y, w0.z, w0.w, w1.x, w1.y, w1.z, w1.w,
                      w2.x, w2.y, w2.z, w2.w};
      #pragma unroll
      for (int r = 0; r < 4; ++r)
        #pragma unroll
        for (int c = 0; c < 12; ++c)
          acc[r][c] = fmaf(xr[r], wc[c], acc[r][c]);
    }
  }

  #pragma unroll
  for (int r = 0; r < 4; ++r) {
    int gr = row0 + ty * 4 + r;
    if (gr >= NNODES) continue;
    #pragma unroll
    for (int q = 0; q < 3; ++q) {
      int c = tx * 12 + q * 4;
      float4 v = make_float4(acc[r][q * 4 + 0], acc[r][q * 4 + 1],
                             acc[r][q * 4 + 2], acc[r][q * 4 + 3]);
      if (c < DO) *(float4*)&h[(size_t)gr * DO + c] = v;
      else        *(float4*)&xR[(size_t)gr * DO + (c - DO)] = v;
    }
  }
}

// ---------------- per-node attention dots ----------------

template<int DO>
__global__ void k_alpha(const float* __restrict__ h, const float* __restrict__ a_s,
                        const float* __restrict__ a_d, float* __restrict__ o_s,
                        float* __restrict__ o_d, int n) {
  int i = blockIdx.x * 256 + threadIdx.x;
  if (i >= n) return;
  float s1 = 0.f, s2 = 0.f;
  #pragma unroll
  for (int c = 0; c < DO; c += 4) {
    float4 hv = *(const float4*)&h[(size_t)i * DO + c];
    s1 += hv.x * a_s[c] + hv.y * a_s[c + 1] + hv.z * a_s[c + 2] + hv.w * a_s[c + 3];
    s2 += hv.x * a_d[c] + hv.y * a_d[c + 1] + hv.z * a_d[c + 2] + hv.w * a_d[c + 3];
  }
  o_s[i] = s1; o_d[i] = s2;
}

// ---------------- fused softmax + aggregate + relu + residual ----------------

template<int DO>
__global__ __launch_bounds__(256) void k_aggregate(
    const float* __restrict__ h, const float* __restrict__ xR,
    const float* __restrict__ as_, const float* __restrict__ ad_,
    const int* __restrict__ srt, const int* __restrict__ offs,
    float* __restrict__ xout, int n) {
  const int lane = threadIdx.x & 63;
  const int node = blockIdx.x * 4 + (threadIdx.x >> 6);
  if (node >= n) return;
  const int start = offs[node], end = offs[node + 1];
  const float adn = ad_[node];

  float m = -INFINITY;
  for (int e = start + lane; e < end; e += 64) {
    float v = as_[srt[e]] + adn;
    v = v > 0.f ? v : 0.2f * v;
    m = fmaxf(m, v);
  }
  #pragma unroll
  for (int off = 32; off; off >>= 1) m = fmaxf(m, __shfl_xor(m, off, 64));

  float ssum = 0.f;
  for (int e = start + lane; e < end; e += 64) {
    float v = as_[srt[e]] + adn;
    v = v > 0.f ? v : 0.2f * v;
    ssum += __expf(v - m);
  }
  #pragma unroll
  for (int off = 32; off; off >>= 1) ssum += __shfl_xor(ssum, off, 64);
  const float inv = 1.f / ssum;

  float acc0 = 0.f, acc1 = 0.f;
  for (int base = start; base < end; base += 64) {
    int e = base + lane;
    float w = 0.f; int s = 0;
    if (e < end) {
      s = srt[e];
      float v = as_[s] + adn;
      v = v > 0.f ? v : 0.2f * v;
      w = __expf(v - m) * inv;
    }
    int cnt = min(64, end - base);
    for (int j = 0; j < cnt; ++j) {
      float a = __shfl(w, j, 64);
      int sj  = __shfl(s, j, 64);
      if (DO >= 64) {
        acc0 += a * h[(size_t)sj * DO + lane];
        if (lane < DO - 64) acc1 += a * h[(size_t)sj * DO + 64 + lane];
      } else {
        if (lane < DO) acc0 += a * h[(size_t)sj * DO + lane];
      }
    }
  }

  if (DO >= 64) {
    xout[(size_t)node * DO + lane] = fmaxf(acc0, 0.f) + xR[(size_t)node * DO + lane];
    if (lane < DO - 64)
      xout[(size_t)node * DO + 64 + lane] =
          fmaxf(acc1, 0.f) + xR[(size_t)node * DO + 64 + lane];
  } else {
    if (lane < DO)
      xout[(size_t)node * DO + lane] = fmaxf(acc0, 0.f) + xR[(size_t)node * DO + lane];
  }
}

// ---------------- launch ----------------

extern "C" void kernel_launch(void* const* d_in, const int* in_sizes, int n_in,
                              void* d_out, int out_size, void* d_ws, size_t ws_size,
                              hipStream_t stream) {
  const int N = NNODES;
  const float* x0 = (const float*)d_in[0];
  const int*   ei = (const int*)d_in[1];
  const int E = in_sizes[1] / 2;

  const float* W0 = (const float*)d_in[2];
  const float* a0s = (const float*)d_in[3];
  const float* a0d = (const float*)d_in[4];
  const float* R0 = (const float*)d_in[5];
  const float* W1 = (const float*)d_in[6];
  const float* a1s = (const float*)d_in[7];
  const float* a1d = (const float*)d_in[8];
  const float* R1 = (const float*)d_in[9];
  const float* W2 = (const float*)d_in[10];
  const float* a2s = (const float*)d_in[11];
  const float* a2d = (const float*)d_in[12];
  const float* R2 = (const float*)d_in[13];
  const float* W3 = (const float*)d_in[14];
  const float* a3s = (const float*)d_in[15];
  const float* a3d = (const float*)d_in[16];
  const float* R3 = (const float*)d_in[17];

  // workspace carve (256B aligned)
  char* p = (char*)d_ws;
  auto alloc = [&](size_t bytes) {
    char* r = p;
    p += (bytes + 255) & ~(size_t)255;
    return r;
  };
  int*   deg  = (int*)alloc((size_t)N * 4);          // reused as cursor
  int*   offs = (int*)alloc((size_t)(N + 1) * 4);
  int*   srt  = (int*)alloc((size_t)(E + N) * 4);
  float* h    = (float*)alloc((size_t)N * 96 * 4);
  float* xR   = (float*)alloc((size_t)N * 96 * 4);
  float* asb  = (float*)alloc((size_t)N * 4);
  float* adb  = (float*)alloc((size_t)N * 4);
  float* xA   = (float*)alloc((size_t)N * 96 * 4);

  // CSR build (dst-sorted, self-loop first in each segment)
  k_deg_init<<<(N + 255) / 256, 256, 0, stream>>>(deg, N);
  k_deg_count<<<(E + 255) / 256, 256, 0, stream>>>(ei, deg, E);
  k_scan<<<1, 256, 0, stream>>>(deg, offs, N);
  k_selfloop<<<(N + 255) / 256, 256, 0, stream>>>(offs, deg, srt, N);
  k_scatter<<<(E + 255) / 256, 256, 0, stream>>>(ei, offs, deg, srt, E);

  // layer 0: K=256, DO=96, in = x0, out = xA
  gemm_fused<256, 96><<<(N + 63) / 64, 256, 0, stream>>>(x0, W0, R0, h, xR);
  k_alpha<96><<<(N + 255) / 256, 256, 0, stream>>>(h, a0s, a0d, asb, adb, N);
  k_aggregate<96><<<(N + 3) / 4, 256, 0, stream>>>(h, xR, asb, adb, srt, offs, xA, N);

  // layer 1: K=96, DO=96, in = xA, out = xA
  gemm_fused<96, 96><<<(N + 63) / 64, 256, 0, stream>>>(xA, W1, R1, h, xR);
  k_alpha<96><<<(N + 255) / 256, 256, 0, stream>>>(h, a1s, a1d, asb, adb, N);
  k_aggregate<96><<<(N + 3) / 4, 256, 0, stream>>>(h, xR, asb, adb, srt, offs, xA, N);

  // layer 2
  gemm_fused<96, 96><<<(N + 63) / 64, 256, 0, stream>>>(xA, W2, R2, h, xR);
  k_alpha<96><<<(N + 255) / 256, 256, 0, stream>>>(h, a2s, a2d, asb, adb, N);
  k_aggregate<96><<<(N + 3) / 4, 256, 0, stream>>>(h, xR, asb, adb, srt, offs, xA, N);

  // layer 3: K=96, DO=48, out -> d_out
  gemm_fused<96, 48><<<(N + 127) / 128, 256, 0, stream>>>(xA, W3, R3, h, xR);
  k_alpha<48><<<(N + 255) / 256, 256, 0, stream>>>(h, a3s, a3d, asb, adb, N);
  k_aggregate<48><<<(N + 3) / 4, 256, 0, stream>>>(h, xR, asb, adb, srt, offs,
                                                   (float*)d_out, N);
}

// Round 2
// 564.998 us; speedup vs baseline: 1.2033x; 1.2033x over previous
//
#include <hip/hip_runtime.h>
#include <hip/hip_bf16.h>
#include <cstdint>
#include <cstddef>

#define NNODES 50000

// ---------------- CSR build ----------------

__global__ void k_deg_init(int* __restrict__ deg, int n) {
  int i = blockIdx.x * 256 + threadIdx.x;
  if (i < n) deg[i] = 1;  // self-loop
}

__global__ void k_deg_count(const int* __restrict__ ei, int* __restrict__ deg, int E) {
  int e = blockIdx.x * 256 + threadIdx.x;
  if (e < E) atomicAdd(&deg[ei[E + e]], 1);
}

__global__ __launch_bounds__(1024) void k_scan(const int* __restrict__ deg,
                                               int* __restrict__ offs, int n) {
  __shared__ int sums[1024];
  int t = threadIdx.x;
  const int CH = (n + 1023) / 1024;
  int c0 = t * CH, c1 = min(n, c0 + CH);
  int s = 0;
  for (int i = c0; i < c1; ++i) s += deg[i];
  sums[t] = s;
  __syncthreads();
  for (int off = 1; off < 1024; off <<= 1) {
    int v = (t >= off) ? sums[t - off] : 0;
    __syncthreads();
    sums[t] += v;
    __syncthreads();
  }
  int run = (t == 0) ? 0 : sums[t - 1];
  if (t == 0) offs[0] = 0;
  for (int i = c0; i < c1; ++i) { run += deg[i]; offs[i + 1] = run; }
}

__global__ void k_selfloop(const int* __restrict__ offs, int* __restrict__ cursor,
                           int* __restrict__ srt, int n) {
  int i = blockIdx.x * 256 + threadIdx.x;
  if (i < n) { cursor[i] = 1; srt[offs[i]] = i; }
}

__global__ void k_scatter(const int* __restrict__ ei, const int* __restrict__ offs,
                          int* __restrict__ cursor, int* __restrict__ srt, int E) {
  int e = blockIdx.x * 256 + threadIdx.x;
  if (e < E) {
    int s = ei[e], d = ei[E + e];
    int pos = offs[d] + atomicAdd(&cursor[d], 1);
    srt[pos] = s;
  }
}

// ---------------- fused GEMM: h = x@W, xR = x@R ----------------

template<int KDIM, int DO, int RPT>
__global__ __launch_bounds__(256) void gemm_fused(
    const float* __restrict__ x, const float* __restrict__ W,
    const float* __restrict__ R, float* __restrict__ h, float* __restrict__ xR) {
  constexpr int DOW = 2 * DO;
  constexpr int TX  = (DOW >= 192) ? 16 : 8;
  constexpr int NTY = 256 / TX;
  constexpr int ROWS = NTY * RPT;
  constexpr int KC = 32;
  constexpr int XP = ROWS + 4;
  constexpr int WP = DOW + 4;
  __shared__ float xt[KC * XP];
  __shared__ float wl[KC * WP];
  const int tid = threadIdx.x;
  const int tx = tid % TX, ty = tid / TX;
  const int row0 = blockIdx.x * ROWS;

  float acc[RPT][12];
  #pragma unroll
  for (int r = 0; r < RPT; ++r)
    #pragma unroll
    for (int c = 0; c < 12; ++c) acc[r][c] = 0.f;

  for (int k0 = 0; k0 < KDIM; k0 += KC) {
    __syncthreads();
    constexpr int NX4 = ROWS * KC / 4;
    for (int id = tid; id < NX4; id += 256) {
      int r = id / (KC / 4), k4 = id % (KC / 4);
      int gr = row0 + r;
      float4 v = make_float4(0.f, 0.f, 0.f, 0.f);
      if (gr < NNODES) v = *(const float4*)&x[(size_t)gr * KDIM + k0 + k4 * 4];
      int kk = k4 * 4;
      xt[(kk + 0) * XP + r] = v.x;
      xt[(kk + 1) * XP + r] = v.y;
      xt[(kk + 2) * XP + r] = v.z;
      xt[(kk + 3) * XP + r] = v.w;
    }
    constexpr int NW4 = DOW * KC / 4;
    for (int id = tid; id < NW4; id += 256) {
      int k = id / (DOW / 4), c = (id % (DOW / 4)) * 4;
      const float* sp = (c < DO) ? &W[(size_t)(k0 + k) * DO + c]
                                 : &R[(size_t)(k0 + k) * DO + (c - DO)];
      *(float4*)&wl[k * WP + c] = *(const float4*)sp;
    }
    __syncthreads();
    #pragma unroll 8
    for (int kk = 0; kk < KC; ++kk) {
      float xr[RPT];
      #pragma unroll
      for (int r = 0; r < RPT; ++r) xr[r] = xt[kk * XP + ty * RPT + r];
      float4 w0 = *(const float4*)&wl[kk * WP + tx * 12 + 0];
      float4 w1 = *(const float4*)&wl[kk * WP + tx * 12 + 4];
      float4 w2 = *(const float4*)&wl[kk * WP + tx * 12 + 8];
      float wc[12] = {w0.x, w0.y, w0.z, w0.w, w1.x, w1.y, w1.z, w1.w,
                      w2.x, w2.y, w2.z, w2.w};
      #pragma unroll
      for (int r = 0; r < RPT; ++r)
        #pragma unroll
        for (int c = 0; c < 12; ++c)
          acc[r][c] = fmaf(xr[r], wc[c], acc[r][c]);
    }
  }

  #pragma unroll
  for (int r = 0; r < RPT; ++r) {
    int gr = row0 + ty * RPT + r;
    if (gr >= NNODES) continue;
    #pragma unroll
    for (int q = 0; q < 3; ++q) {
      int c = tx * 12 + q * 4;
      float4 v = make_float4(acc[r][q * 4 + 0], acc[r][q * 4 + 1],
                             acc[r][q * 4 + 2], acc[r][q * 4 + 3]);
      if (c < DO) *(float4*)&h[(size_t)gr * DO + c] = v;
      else        *(float4*)&xR[(size_t)gr * DO + (c - DO)] = v;
    }
  }
}

// ---------------- per-node attention dots ----------------

template<int DO>
__global__ void k_alpha(const float* __restrict__ h, const float* __restrict__ a_s,
                        const float* __restrict__ a_d, float* __restrict__ o_s,
                        float* __restrict__ o_d, int n) {
  int i = blockIdx.x * 256 + threadIdx.x;
  if (i >= n) return;
  float s1 = 0.f, s2 = 0.f;
  #pragma unroll
  for (int c = 0; c < DO; c += 4) {
    float4 hv = *(const float4*)&h[(size_t)i * DO + c];
    s1 += hv.x * a_s[c] + hv.y * a_s[c + 1] + hv.z * a_s[c + 2] + hv.w * a_s[c + 3];
    s2 += hv.x * a_d[c] + hv.y * a_d[c + 1] + hv.z * a_d[c + 2] + hv.w * a_d[c + 3];
  }
  o_s[i] = s1; o_d[i] = s2;
}

// ---------------- fused softmax + aggregate + relu + residual ----------------
// One wave per node. Phase 1/2: edge-parallel logit max + expsum, caching
// (src, w) in wave-private LDS. Phase 3: lane = feature, 8-deep unrolled edge
// loop so 8 independent gathers of h rows are in flight (hides L2/L3 latency).

template<int DO>
__global__ __launch_bounds__(256) void k_aggregate(
    const float* __restrict__ h, const float* __restrict__ xR,
    const float* __restrict__ as_, const float* __restrict__ ad_,
    const int* __restrict__ srt, const int* __restrict__ offs,
    float* __restrict__ xout, int n) {
  constexpr int CAP = 256;
  __shared__ float wbuf[4][CAP];
  __shared__ int   sbuf[4][CAP];
  const int lane = threadIdx.x & 63;
  const int wid  = threadIdx.x >> 6;
  const int node = blockIdx.x * 4 + wid;
  if (node >= n) return;
  const int start = offs[node];
  const int deg   = offs[node + 1] - start;
  const float adn = ad_[node];

  // phase 1: per-edge logits, running max; cache v and src in LDS
  float m = -INFINITY;
  for (int idx = lane; idx < deg; idx += 64) {
    int s = srt[start + idx];
    float v = as_[s] + adn;
    v = v > 0.f ? v : 0.2f * v;
    if (idx < CAP) { wbuf[wid][idx] = v; sbuf[wid][idx] = s; }
    m = fmaxf(m, v);
  }
  #pragma unroll
  for (int off = 32; off; off >>= 1) m = fmaxf(m, __shfl_xor(m, off, 64));

  // phase 2: exp & sum (unnormalized weights back into LDS)
  float ssum = 0.f;
  for (int idx = lane; idx < deg; idx += 64) {
    float v;
    if (idx < CAP) v = wbuf[wid][idx];
    else {
      int s = srt[start + idx];
      v = as_[s] + adn;
      v = v > 0.f ? v : 0.2f * v;
    }
    float w = __expf(v - m);
    if (idx < CAP) wbuf[wid][idx] = w;
    ssum += w;
  }
  #pragma unroll
  for (int off = 32; off; off >>= 1) ssum += __shfl_xor(ssum, off, 64);
  const float inv = 1.f / ssum;

  // phase 3: feature-parallel gather, 8-deep unrolled edge loop
  float acc0 = 0.f, acc1 = 0.f;
  const int dcap = min(deg, CAP);
  for (int base = 0; base < dcap; base += 8) {
    float wv[8]; int sv[8];
    #pragma unroll
    for (int u = 0; u < 8; ++u) {
      int e = base + u;
      bool ok = e < dcap;
      sv[u] = sbuf[wid][ok ? e : 0];
      wv[u] = ok ? wbuf[wid][e] : 0.f;
    }
    float h0[8], h1[8];
    #pragma unroll
    for (int u = 0; u < 8; ++u) {
      const float* hp = &h[(size_t)sv[u] * DO];
      h0[u] = (DO >= 64 || lane < DO) ? hp[lane] : 0.f;
      if (DO > 64) h1[u] = (lane < DO - 64) ? hp[64 + lane] : 0.f;
    }
    #pragma unroll
    for (int u = 0; u < 8; ++u) {
      acc0 += wv[u] * h0[u];
      if (DO > 64) acc1 += wv[u] * h1[u];
    }
  }
  // rare overflow path (deg > CAP)
  for (int e = CAP; e < deg; ++e) {
    int s = srt[start + e];
    float v = as_[s] + adn;
    v = v > 0.f ? v : 0.2f * v;
    float w = __expf(v - m);
    const float* hp = &h[(size_t)s * DO];
    acc0 += w * ((DO >= 64 || lane < DO) ? hp[lane] : 0.f);
    if (DO > 64 && lane < DO - 64) acc1 += w * hp[64 + lane];
  }

  const size_t b = (size_t)node * DO;
  if (DO >= 64) {
    xout[b + lane] = fmaxf(acc0 * inv, 0.f) + xR[b + lane];
    if (lane < DO - 64)
      xout[b + 64 + lane] = fmaxf(acc1 * inv, 0.f) + xR[b + 64 + lane];
  } else if (lane < DO) {
    xout[b + lane] = fmaxf(acc0 * inv, 0.f) + xR[b + lane];
  }
}

// ---------------- launch ----------------

extern "C" void kernel_launch(void* const* d_in, const int* in_sizes, int n_in,
                              void* d_out, int out_size, void* d_ws, size_t ws_size,
                              hipStream_t stream) {
  const int N = NNODES;
  const float* x0 = (const float*)d_in[0];
  const int*   ei = (const int*)d_in[1];
  const int E = in_sizes[1] / 2;

  const float* W0 = (const float*)d_in[2];
  const float* a0s = (const float*)d_in[3];
  const float* a0d = (const float*)d_in[4];
  const float* R0 = (const float*)d_in[5];
  const float* W1 = (const float*)d_in[6];
  const float* a1s = (const float*)d_in[7];
  const float* a1d = (const float*)d_in[8];
  const float* R1 = (const float*)d_in[9];
  const float* W2 = (const float*)d_in[10];
  const float* a2s = (const float*)d_in[11];
  const float* a2d = (const float*)d_in[12];
  const float* R2 = (const float*)d_in[13];
  const float* W3 = (const float*)d_in[14];
  const float* a3s = (const float*)d_in[15];
  const float* a3d = (const float*)d_in[16];
  const float* R3 = (const float*)d_in[17];

  char* p = (char*)d_ws;
  auto alloc = [&](size_t bytes) {
    char* r = p;
    p += (bytes + 255) & ~(size_t)255;
    return r;
  };
  int*   deg  = (int*)alloc((size_t)N * 4);          // reused as cursor
  int*   offs = (int*)alloc((size_t)(N + 1) * 4);
  int*   srt  = (int*)alloc((size_t)(E + N) * 4);
  float* h    = (float*)alloc((size_t)N * 96 * 4);
  float* xR   = (float*)alloc((size_t)N * 96 * 4);
  float* asb  = (float*)alloc((size_t)N * 4);
  float* adb  = (float*)alloc((size_t)N * 4);
  float* xA   = (float*)alloc((size_t)N * 96 * 4);

  // CSR build (dst-sorted, self-loop first in each segment)
  k_deg_init<<<(N + 255) / 256, 256, 0, stream>>>(deg, N);
  k_deg_count<<<(E + 255) / 256, 256, 0, stream>>>(ei, deg, E);
  k_scan<<<1, 1024, 0, stream>>>(deg, offs, N);
  k_selfloop<<<(N + 255) / 256, 256, 0, stream>>>(offs, deg, srt, N);
  k_scatter<<<(E + 255) / 256, 256, 0, stream>>>(ei, offs, deg, srt, E);

  // layer 0: K=256, DO=96
  gemm_fused<256, 96, 3><<<(N + 47) / 48, 256, 0, stream>>>(x0, W0, R0, h, xR);
  k_alpha<96><<<(N + 255) / 256, 256, 0, stream>>>(h, a0s, a0d, asb, adb, N);
  k_aggregate<96><<<(N + 3) / 4, 256, 0, stream>>>(h, xR, asb, adb, srt, offs, xA, N);

  // layer 1
  gemm_fused<96, 96, 3><<<(N + 47) / 48, 256, 0, stream>>>(xA, W1, R1, h, xR);
  k_alpha<96><<<(N + 255) / 256, 256, 0, stream>>>(h, a1s, a1d, asb, adb, N);
  k_aggregate<96><<<(N + 3) / 4, 256, 0, stream>>>(h, xR, asb, adb, srt, offs, xA, N);

  // layer 2
  gemm_fused<96, 96, 3><<<(N + 47) / 48, 256, 0, stream>>>(xA, W2, R2, h, xR);
  k_alpha<96><<<(N + 255) / 256, 256, 0, stream>>>(h, a2s, a2d, asb, adb, N);
  k_aggregate<96><<<(N + 3) / 4, 256, 0, stream>>>(h, xR, asb, adb, srt, offs, xA, N);

  // layer 3: K=96, DO=48 -> d_out
  gemm_fused<96, 48, 2><<<(N + 63) / 64, 256, 0, stream>>>(xA, W3, R3, h, xR);
  k_alpha<48><<<(N + 255) / 256, 256, 0, stream>>>(h, a3s, a3d, asb, adb, N);
  k_aggregate<48><<<(N + 3) / 4, 256, 0, stream>>>(h, xR, asb, adb, srt, offs,
                                                   (float*)d_out, N);
}

// Round 3
// 445.315 us; speedup vs baseline: 1.5267x; 1.2688x over previous
//
#include <hip/hip_runtime.h>
#include <hip/hip_bf16.h>
#include <cstdint>
#include <cstddef>

#define NNODES 50000

using s8v = __attribute__((ext_vector_type(8))) short;
using f4v = __attribute__((ext_vector_type(4))) float;

__device__ __forceinline__ unsigned short f2bf(float f) {
  union { float f; uint32_t u; } x; x.f = f;
  uint32_t r = x.u + 0x7FFF + ((x.u >> 16) & 1);  // RNE
  return (unsigned short)(r >> 16);
}

// ---------------- CSR build ----------------

__global__ void k_deg_init(int* __restrict__ deg, int n) {
  int i = blockIdx.x * 256 + threadIdx.x;
  if (i < n) deg[i] = 1;  // self-loop
}

__global__ void k_deg_count(const int* __restrict__ ei, int* __restrict__ deg, int E) {
  int e = blockIdx.x * 256 + threadIdx.x;
  if (e < E) atomicAdd(&deg[ei[E + e]], 1);
}

__global__ __launch_bounds__(1024) void k_scan(const int* __restrict__ deg,
                                               int* __restrict__ offs, int n) {
  __shared__ int sums[1024];
  int t = threadIdx.x;
  const int CH = (n + 1023) / 1024;
  int c0 = t * CH, c1 = min(n, c0 + CH);
  int s = 0;
  for (int i = c0; i < c1; ++i) s += deg[i];
  sums[t] = s;
  __syncthreads();
  for (int off = 1; off < 1024; off <<= 1) {
    int v = (t >= off) ? sums[t - off] : 0;
    __syncthreads();
    sums[t] += v;
    __syncthreads();
  }
  int run = (t == 0) ? 0 : sums[t - 1];
  if (t == 0) offs[0] = 0;
  for (int i = c0; i < c1; ++i) { run += deg[i]; offs[i + 1] = run; }
}

__global__ void k_selfloop(const int* __restrict__ offs, int* __restrict__ cursor,
                           int* __restrict__ srt, int n) {
  int i = blockIdx.x * 256 + threadIdx.x;
  if (i < n) { cursor[i] = 1; srt[offs[i]] = i; }
}

__global__ void k_scatter(const int* __restrict__ ei, const int* __restrict__ offs,
                          int* __restrict__ cursor, int* __restrict__ srt, int E) {
  int e = blockIdx.x * 256 + threadIdx.x;
  if (e < E) {
    int s = ei[e], d = ei[E + e];
    int pos = offs[d] + atomicAdd(&cursor[d], 1);
    srt[pos] = s;
  }
}

// ---------------- weight pre-transpose + bf16 convert ----------------
// Wt[n][k] = bf16( n < DO ? W[k][n] : R[k][n-DO] ), row-major [2*DO][K]

__global__ void k_wt(const float* __restrict__ W, const float* __restrict__ R,
                     unsigned short* __restrict__ Wt, int K, int DO) {
  int idx = blockIdx.x * 256 + threadIdx.x;
  int tot = 2 * DO * K;
  if (idx >= tot) return;
  int n = idx / K, k = idx % K;
  float v = (n < DO) ? W[(size_t)k * DO + n] : R[(size_t)k * DO + (n - DO)];
  Wt[idx] = f2bf(v);
}

// ---------------- MFMA GEMM: [h | xR] = bf16(x) @ [W | R] ----------------
// BM=64 rows/block, 4 waves each own a 16-row band; BN = 2*DO = NT*16.
// A_lds/B_lds rows padded to 40 ushorts (80 B) -> 16B-aligned frag reads,
// max 2-way bank aliasing (free).

template<int KDIM, int NT>   // NT = DOW/16 (12 for DO=96, 6 for DO=48)
__global__ __launch_bounds__(256) void gemm_mfma(
    const float* __restrict__ x, const unsigned short* __restrict__ Wt,
    float* __restrict__ h, float* __restrict__ xR) {
  constexpr int DOW = NT * 16;
  constexpr int DO  = DOW / 2;
  constexpr int BM  = 64;
  constexpr int AP  = 40;   // row pitch in ushorts (32 data + 8 pad)
  __shared__ __align__(16) unsigned short Al[BM * AP];
  __shared__ __align__(16) unsigned short Bl[DOW * AP];

  const int tid  = threadIdx.x;
  const int wave = tid >> 6;
  const int lane = tid & 63;
  const int row0 = blockIdx.x * BM;

  f4v acc[NT];
  #pragma unroll
  for (int t = 0; t < NT; ++t) acc[t] = (f4v)(0.f);

  const int fr = lane & 15;   // frag row/col index
  const int fq = lane >> 4;   // k-quarter

  for (int k0 = 0; k0 < KDIM; k0 += 32) {
    __syncthreads();
    // stage A: slot = tid; row = tid>>2, ko = (tid&3)*8
    {
      int r = tid >> 2, ko = (tid & 3) * 8;
      int gr = row0 + r;
      s8v out;
      if (gr < NNODES) {
        const float* xp = &x[(size_t)gr * KDIM + k0 + ko];
        float4 v0 = *(const float4*)(xp);
        float4 v1 = *(const float4*)(xp + 4);
        out[0] = (short)f2bf(v0.x); out[1] = (short)f2bf(v0.y);
        out[2] = (short)f2bf(v0.z); out[3] = (short)f2bf(v0.w);
        out[4] = (short)f2bf(v1.x); out[5] = (short)f2bf(v1.y);
        out[6] = (short)f2bf(v1.z); out[7] = (short)f2bf(v1.w);
      } else {
        out = (s8v)(0);
      }
      *(s8v*)&Al[r * AP + ko] = out;
    }
    // stage B: DOW*4 slots of 8 bf16
    for (int s = tid; s < DOW * 4; s += 256) {
      int n = s >> 2, ko = (s & 3) * 8;
      s8v v = *(const s8v*)&Wt[(size_t)n * KDIM + k0 + ko];
      *(s8v*)&Bl[n * AP + ko] = v;
    }
    __syncthreads();

    s8v a = *(const s8v*)&Al[(wave * 16 + fr) * AP + fq * 8];
    #pragma unroll
    for (int t = 0; t < NT; ++t) {
      s8v b = *(const s8v*)&Bl[(t * 16 + fr) * AP + fq * 8];
      acc[t] = __builtin_amdgcn_mfma_f32_16x16x32_bf16(a, b, acc[t], 0, 0, 0);
    }
  }

  // epilogue: D col = lane&15, row = (lane>>4)*4 + reg
  #pragma unroll
  for (int t = 0; t < NT; ++t) {
    int gcol = t * 16 + fr;
    float* dst; int c;
    if (gcol < DO) { dst = h; c = gcol; }
    else           { dst = xR; c = gcol - DO; }
    #pragma unroll
    for (int r = 0; r < 4; ++r) {
      int grow = row0 + wave * 16 + fq * 4 + r;
      if (grow < NNODES) dst[(size_t)grow * DO + c] = acc[t][r];
    }
  }
}

// ---------------- per-node attention dots ----------------

template<int DO>
__global__ void k_alpha(const float* __restrict__ h, const float* __restrict__ a_s,
                        const float* __restrict__ a_d, float* __restrict__ o_s,
                        float* __restrict__ o_d, int n) {
  int i = blockIdx.x * 256 + threadIdx.x;
  if (i >= n) return;
  float s1 = 0.f, s2 = 0.f;
  #pragma unroll
  for (int c = 0; c < DO; c += 4) {
    float4 hv = *(const float4*)&h[(size_t)i * DO + c];
    s1 += hv.x * a_s[c] + hv.y * a_s[c + 1] + hv.z * a_s[c + 2] + hv.w * a_s[c + 3];
    s2 += hv.x * a_d[c] + hv.y * a_d[c + 1] + hv.z * a_d[c + 2] + hv.w * a_d[c + 3];
  }
  o_s[i] = s1; o_d[i] = s2;
}

// ---------------- fused softmax + aggregate + relu + residual ----------------

template<int DO>
__global__ __launch_bounds__(256) void k_aggregate(
    const float* __restrict__ h, const float* __restrict__ xR,
    const float* __restrict__ as_, const float* __restrict__ ad_,
    const int* __restrict__ srt, const int* __restrict__ offs,
    float* __restrict__ xout, int n) {
  constexpr int CAP = 256;
  __shared__ float wbuf[4][CAP];
  __shared__ int   sbuf[4][CAP];
  const int lane = threadIdx.x & 63;
  const int wid  = threadIdx.x >> 6;
  const int node = blockIdx.x * 4 + wid;
  if (node >= n) return;
  const int start = offs[node];
  const int deg   = offs[node + 1] - start;
  const float adn = ad_[node];

  float m = -INFINITY;
  for (int idx = lane; idx < deg; idx += 64) {
    int s = srt[start + idx];
    float v = as_[s] + adn;
    v = v > 0.f ? v : 0.2f * v;
    if (idx < CAP) { wbuf[wid][idx] = v; sbuf[wid][idx] = s; }
    m = fmaxf(m, v);
  }
  #pragma unroll
  for (int off = 32; off; off >>= 1) m = fmaxf(m, __shfl_xor(m, off, 64));

  float ssum = 0.f;
  for (int idx = lane; idx < deg; idx += 64) {
    float v;
    if (idx < CAP) v = wbuf[wid][idx];
    else {
      int s = srt[start + idx];
      v = as_[s] + adn;
      v = v > 0.f ? v : 0.2f * v;
    }
    float w = __expf(v - m);
    if (idx < CAP) wbuf[wid][idx] = w;
    ssum += w;
  }
  #pragma unroll
  for (int off = 32; off; off >>= 1) ssum += __shfl_xor(ssum, off, 64);
  const float inv = 1.f / ssum;

  float acc0 = 0.f, acc1 = 0.f;
  const int dcap = min(deg, CAP);
  for (int base = 0; base < dcap; base += 8) {
    float wv[8]; int sv[8];
    #pragma unroll
    for (int u = 0; u < 8; ++u) {
      int e = base + u;
      bool ok = e < dcap;
      sv[u] = sbuf[wid][ok ? e : 0];
      wv[u] = ok ? wbuf[wid][e] : 0.f;
    }
    float h0[8], h1[8];
    #pragma unroll
    for (int u = 0; u < 8; ++u) {
      const float* hp = &h[(size_t)sv[u] * DO];
      h0[u] = (DO >= 64 || lane < DO) ? hp[lane] : 0.f;
      if (DO > 64) h1[u] = (lane < DO - 64) ? hp[64 + lane] : 0.f;
    }
    #pragma unroll
    for (int u = 0; u < 8; ++u) {
      acc0 += wv[u] * h0[u];
      if (DO > 64) acc1 += wv[u] * h1[u];
    }
  }
  for (int e = CAP; e < deg; ++e) {
    int s = srt[start + e];
    float v = as_[s] + adn;
    v = v > 0.f ? v : 0.2f * v;
    float w = __expf(v - m);
    const float* hp = &h[(size_t)s * DO];
    acc0 += w * ((DO >= 64 || lane < DO) ? hp[lane] : 0.f);
    if (DO > 64 && lane < DO - 64) acc1 += w * hp[64 + lane];
  }

  const size_t b = (size_t)node * DO;
  if (DO >= 64) {
    xout[b + lane] = fmaxf(acc0 * inv, 0.f) + xR[b + lane];
    if (lane < DO - 64)
      xout[b + 64 + lane] = fmaxf(acc1 * inv, 0.f) + xR[b + 64 + lane];
  } else if (lane < DO) {
    xout[b + lane] = fmaxf(acc0 * inv, 0.f) + xR[b + lane];
  }
}

// ---------------- launch ----------------

extern "C" void kernel_launch(void* const* d_in, const int* in_sizes, int n_in,
                              void* d_out, int out_size, void* d_ws, size_t ws_size,
                              hipStream_t stream) {
  const int N = NNODES;
  const float* x0 = (const float*)d_in[0];
  const int*   ei = (const int*)d_in[1];
  const int E = in_sizes[1] / 2;

  const float* W0 = (const float*)d_in[2];
  const float* a0s = (const float*)d_in[3];
  const float* a0d = (const float*)d_in[4];
  const float* R0 = (const float*)d_in[5];
  const float* W1 = (const float*)d_in[6];
  const float* a1s = (const float*)d_in[7];
  const float* a1d = (const float*)d_in[8];
  const float* R1 = (const float*)d_in[9];
  const float* W2 = (const float*)d_in[10];
  const float* a2s = (const float*)d_in[11];
  const float* a2d = (const float*)d_in[12];
  const float* R2 = (const float*)d_in[13];
  const float* W3 = (const float*)d_in[14];
  const float* a3s = (const float*)d_in[15];
  const float* a3d = (const float*)d_in[16];
  const float* R3 = (const float*)d_in[17];

  char* p = (char*)d_ws;
  auto alloc = [&](size_t bytes) {
    char* r = p;
    p += (bytes + 255) & ~(size_t)255;
    return r;
  };
  int*   deg  = (int*)alloc((size_t)N * 4);          // reused as cursor
  int*   offs = (int*)alloc((size_t)(N + 1) * 4);
  int*   srt  = (int*)alloc((size_t)(E + N) * 4);
  float* h    = (float*)alloc((size_t)N * 96 * 4);
  float* xR   = (float*)alloc((size_t)N * 96 * 4);
  float* asb  = (float*)alloc((size_t)N * 4);
  float* adb  = (float*)alloc((size_t)N * 4);
  float* xA   = (float*)alloc((size_t)N * 96 * 4);
  unsigned short* Wt0 = (unsigned short*)alloc((size_t)192 * 256 * 2);
  unsigned short* Wt1 = (unsigned short*)alloc((size_t)192 * 96 * 2);
  unsigned short* Wt2 = (unsigned short*)alloc((size_t)192 * 96 * 2);
  unsigned short* Wt3 = (unsigned short*)alloc((size_t)96 * 96 * 2);

  // CSR build (dst-sorted, self-loop first in each segment)
  k_deg_init<<<(N + 255) / 256, 256, 0, stream>>>(deg, N);
  k_deg_count<<<(E + 255) / 256, 256, 0, stream>>>(ei, deg, E);
  k_scan<<<1, 1024, 0, stream>>>(deg, offs, N);
  k_selfloop<<<(N + 255) / 256, 256, 0, stream>>>(offs, deg, srt, N);
  k_scatter<<<(E + 255) / 256, 256, 0, stream>>>(ei, offs, deg, srt, E);

  // weight convert/transpose (bf16)
  k_wt<<<(192 * 256 + 255) / 256, 256, 0, stream>>>(W0, R0, Wt0, 256, 96);
  k_wt<<<(192 * 96 + 255) / 256, 256, 0, stream>>>(W1, R1, Wt1, 96, 96);
  k_wt<<<(192 * 96 + 255) / 256, 256, 0, stream>>>(W2, R2, Wt2, 96, 96);
  k_wt<<<(96 * 96 + 255) / 256, 256, 0, stream>>>(W3, R3, Wt3, 96, 48);

  const int GB = (N + 63) / 64;

  // layer 0: K=256, DO=96
  gemm_mfma<256, 12><<<GB, 256, 0, stream>>>(x0, Wt0, h, xR);
  k_alpha<96><<<(N + 255) / 256, 256, 0, stream>>>(h, a0s, a0d, asb, adb, N);
  k_aggregate<96><<<(N + 3) / 4, 256, 0, stream>>>(h, xR, asb, adb, srt, offs, xA, N);

  // layer 1
  gemm_mfma<96, 12><<<GB, 256, 0, stream>>>(xA, Wt1, h, xR);
  k_alpha<96><<<(N + 255) / 256, 256, 0, stream>>>(h, a1s, a1d, asb, adb, N);
  k_aggregate<96><<<(N + 3) / 4, 256, 0, stream>>>(h, xR, asb, adb, srt, offs, xA, N);

  // layer 2
  gemm_mfma<96, 12><<<GB, 256, 0, stream>>>(xA, Wt2, h, xR);
  k_alpha<96><<<(N + 255) / 256, 256, 0, stream>>>(h, a2s, a2d, asb, adb, N);
  k_aggregate<96><<<(N + 3) / 4, 256, 0, stream>>>(h, xR, asb, adb, srt, offs, xA, N);

  // layer 3: K=96, DO=48 -> d_out
  gemm_mfma<96, 6><<<GB, 256, 0, stream>>>(xA, Wt3, h, xR);
  k_alpha<48><<<(N + 255) / 256, 256, 0, stream>>>(h, a3s, a3d, asb, adb, N);
  k_aggregate<48><<<(N + 3) / 4, 256, 0, stream>>>(h, xR, asb, adb, srt, offs,
                                                   (float*)d_out, N);
}

// Round 4
// 357.327 us; speedup vs baseline: 1.9026x; 1.2462x over previous
//
#include <hip/hip_runtime.h>
#include <hip/hip_bf16.h>
#include <cstdint>
#include <cstddef>

#define NNODES 50000

using s8v = __attribute__((ext_vector_type(8))) short;
using f4v = __attribute__((ext_vector_type(4))) float;

__device__ __forceinline__ unsigned short f2bf(float f) {
  union { float f; uint32_t u; } x; x.f = f;
  uint32_t r = x.u + 0x7FFF + ((x.u >> 16) & 1);  // RNE
  return (unsigned short)(r >> 16);
}

// ---------------- CSR build ----------------

__global__ void k_deg_init(int* __restrict__ deg, int n) {
  int i = blockIdx.x * 256 + threadIdx.x;
  if (i < n) deg[i] = 1;  // self-loop
}

__global__ void k_deg_count(const int* __restrict__ ei, int* __restrict__ deg, int E) {
  int e = blockIdx.x * 256 + threadIdx.x;
  if (e < E) atomicAdd(&deg[ei[E + e]], 1);
}

// 3-phase parallel exclusive scan: offs[i+1] = inclusive prefix of deg[0..i]
__global__ __launch_bounds__(256) void k_scan1(const int* __restrict__ deg,
                                               int* __restrict__ offs,
                                               int* __restrict__ blksum, int n) {
  __shared__ int part[256];
  const int tid = threadIdx.x;
  const int base = blockIdx.x * 2048 + tid * 8;
  int v[8]; int s = 0;
  #pragma unroll
  for (int u = 0; u < 8; ++u) {
    int i = base + u;
    v[u] = (i < n) ? deg[i] : 0;
    s += v[u];
  }
  part[tid] = s;
  __syncthreads();
  for (int off = 1; off < 256; off <<= 1) {
    int t = (tid >= off) ? part[tid - off] : 0;
    __syncthreads();
    part[tid] += t;
    __syncthreads();
  }
  int run = (tid == 0) ? 0 : part[tid - 1];
  #pragma unroll
  for (int u = 0; u < 8; ++u) {
    int i = base + u;
    run += v[u];
    if (i < n) offs[i + 1] = run;
  }
  if (tid == 255) blksum[blockIdx.x] = part[255];
}

__global__ void k_scan2(int* __restrict__ blksum, int nb) {
  int t = threadIdx.x;
  int v = (t < nb) ? blksum[t] : 0;
  for (int off = 1; off < 64; off <<= 1) {
    int o = __shfl_up(v, off, 64);
    if (t >= off) v += o;
  }
  if (t < nb) blksum[t] = v;  // inclusive block-sum scan
}

__global__ void k_scan3(int* __restrict__ offs, const int* __restrict__ blksum, int n) {
  int i = blockIdx.x * 256 + threadIdx.x;
  if (i < n) {
    int b = i >> 11;
    if (b > 0) offs[i + 1] += blksum[b - 1];
  }
  if (i == 0) offs[0] = 0;
}

__global__ void k_selfloop(const int* __restrict__ offs, int* __restrict__ cursor,
                           int* __restrict__ srt, int n) {
  int i = blockIdx.x * 256 + threadIdx.x;
  if (i < n) { cursor[i] = 1; srt[offs[i]] = i; }
}

__global__ void k_scatter(const int* __restrict__ ei, const int* __restrict__ offs,
                          int* __restrict__ cursor, int* __restrict__ srt, int E) {
  int e = blockIdx.x * 256 + threadIdx.x;
  if (e < E) {
    int s = ei[e], d = ei[E + e];
    int pos = offs[d] + atomicAdd(&cursor[d], 1);
    srt[pos] = s;
  }
}

// ---------------- weight pre-transpose + bf16 convert ----------------

__global__ void k_wt(const float* __restrict__ W, const float* __restrict__ R,
                     unsigned short* __restrict__ Wt, int K, int DO) {
  int idx = blockIdx.x * 256 + threadIdx.x;
  int tot = 2 * DO * K;
  if (idx >= tot) return;
  int n = idx / K, k = idx % K;
  float v = (n < DO) ? W[(size_t)k * DO + n] : R[(size_t)k * DO + (n - DO)];
  Wt[idx] = f2bf(v);
}

// ---------------- MFMA GEMM + fused alpha dots ----------------
// BM=64 rows/block, 4 waves each own a 16-row band; BN = 2*DO = NT*16.
// Epilogue also computes asb = h@a_s, adb = h@a_d via 16-lane shfl reduce.

template<int KDIM, int NT>   // NT = DOW/16
__global__ __launch_bounds__(256) void gemm_mfma(
    const float* __restrict__ x, const unsigned short* __restrict__ Wt,
    const float* __restrict__ a_s, const float* __restrict__ a_d,
    float* __restrict__ h, float* __restrict__ xR,
    float* __restrict__ asb, float* __restrict__ adb) {
  constexpr int DOW = NT * 16;
  constexpr int DO  = DOW / 2;
  constexpr int NH  = NT / 2;   // tiles belonging to h
  constexpr int BM  = 64;
  constexpr int AP  = 40;
  __shared__ __align__(16) unsigned short Al[BM * AP];
  __shared__ __align__(16) unsigned short Bl[DOW * AP];

  const int tid  = threadIdx.x;
  const int wave = tid >> 6;
  const int lane = tid & 63;
  const int row0 = blockIdx.x * BM;

  f4v acc[NT];
  #pragma unroll
  for (int t = 0; t < NT; ++t) acc[t] = (f4v)(0.f);

  const int fr = lane & 15;
  const int fq = lane >> 4;

  for (int k0 = 0; k0 < KDIM; k0 += 32) {
    __syncthreads();
    {
      int r = tid >> 2, ko = (tid & 3) * 8;
      int gr = row0 + r;
      s8v out;
      if (gr < NNODES) {
        const float* xp = &x[(size_t)gr * KDIM + k0 + ko];
        float4 v0 = *(const float4*)(xp);
        float4 v1 = *(const float4*)(xp + 4);
        out[0] = (short)f2bf(v0.x); out[1] = (short)f2bf(v0.y);
        out[2] = (short)f2bf(v0.z); out[3] = (short)f2bf(v0.w);
        out[4] = (short)f2bf(v1.x); out[5] = (short)f2bf(v1.y);
        out[6] = (short)f2bf(v1.z); out[7] = (short)f2bf(v1.w);
      } else {
        out = (s8v)(0);
      }
      *(s8v*)&Al[r * AP + ko] = out;
    }
    for (int s = tid; s < DOW * 4; s += 256) {
      int n = s >> 2, ko = (s & 3) * 8;
      s8v v = *(const s8v*)&Wt[(size_t)n * KDIM + k0 + ko];
      *(s8v*)&Bl[n * AP + ko] = v;
    }
    __syncthreads();

    s8v a = *(const s8v*)&Al[(wave * 16 + fr) * AP + fq * 8];
    #pragma unroll
    for (int t = 0; t < NT; ++t) {
      s8v b = *(const s8v*)&Bl[(t * 16 + fr) * AP + fq * 8];
      acc[t] = __builtin_amdgcn_mfma_f32_16x16x32_bf16(a, b, acc[t], 0, 0, 0);
    }
  }

  // C write: D col = lane&15, row = (lane>>4)*4 + reg
  #pragma unroll
  for (int t = 0; t < NT; ++t) {
    int gcol = t * 16 + fr;
    float* dst; int c;
    if (t < NH) { dst = h; c = gcol; }
    else        { dst = xR; c = gcol - DO; }
    #pragma unroll
    for (int r = 0; r < 4; ++r) {
      int grow = row0 + wave * 16 + fq * 4 + r;
      if (grow < NNODES) dst[(size_t)grow * DO + c] = acc[t][r];
    }
  }

  // fused alpha dots over h columns
  float avs[NH], avd[NH];
  #pragma unroll
  for (int t = 0; t < NH; ++t) {
    avs[t] = a_s[t * 16 + fr];
    avd[t] = a_d[t * 16 + fr];
  }
  #pragma unroll
  for (int r = 0; r < 4; ++r) {
    float ps = 0.f, pd = 0.f;
    #pragma unroll
    for (int t = 0; t < NH; ++t) {
      ps = fmaf(acc[t][r], avs[t], ps);
      pd = fmaf(acc[t][r], avd[t], pd);
    }
    #pragma unroll
    for (int off = 1; off < 16; off <<= 1) {
      ps += __shfl_xor(ps, off, 64);
      pd += __shfl_xor(pd, off, 64);
    }
    int grow = row0 + wave * 16 + fq * 4 + r;
    if (fr == 0 && grow < NNODES) { asb[grow] = ps; adb[grow] = pd; }
  }
}

// ---------------- fused softmax + aggregate + relu + residual ----------------

template<int DO>
__global__ __launch_bounds__(256) void k_aggregate(
    const float* __restrict__ h, const float* __restrict__ xR,
    const float* __restrict__ as_, const float* __restrict__ ad_,
    const int* __restrict__ srt, const int* __restrict__ offs,
    float* __restrict__ xout, int n) {
  constexpr int CAP = 256;
  __shared__ float wbuf[4][CAP];
  __shared__ int   sbuf[4][CAP];
  const int lane = threadIdx.x & 63;
  const int wid  = threadIdx.x >> 6;
  const int node = blockIdx.x * 4 + wid;
  if (node >= n) return;
  const int start = offs[node];
  const int deg   = offs[node + 1] - start;
  const float adn = ad_[node];

  float m = -INFINITY;
  for (int idx = lane; idx < deg; idx += 64) {
    int s = srt[start + idx];
    float v = as_[s] + adn;
    v = v > 0.f ? v : 0.2f * v;
    if (idx < CAP) { wbuf[wid][idx] = v; sbuf[wid][idx] = s; }
    m = fmaxf(m, v);
  }
  #pragma unroll
  for (int off = 32; off; off >>= 1) m = fmaxf(m, __shfl_xor(m, off, 64));

  float ssum = 0.f;
  for (int idx = lane; idx < deg; idx += 64) {
    float v;
    if (idx < CAP) v = wbuf[wid][idx];
    else {
      int s = srt[start + idx];
      v = as_[s] + adn;
      v = v > 0.f ? v : 0.2f * v;
    }
    float w = __expf(v - m);
    if (idx < CAP) wbuf[wid][idx] = w;
    ssum += w;
  }
  #pragma unroll
  for (int off = 32; off; off >>= 1) ssum += __shfl_xor(ssum, off, 64);
  const float inv = 1.f / ssum;

  // phase 3: feature-parallel gather. DO=96: lane<48 owns float2 of features.
  const int dcap = min(deg, CAP);
  float2 acc = make_float2(0.f, 0.f);
  const bool act = (DO == 96) ? (lane < 48) : (lane < DO);
  for (int base = 0; base < dcap; base += 8) {
    float wv[8]; int sv[8];
    #pragma unroll
    for (int u = 0; u < 8; ++u) {
      int e = base + u;
      bool ok = e < dcap;
      sv[u] = sbuf[wid][ok ? e : 0];
      wv[u] = ok ? wbuf[wid][e] : 0.f;
    }
    if (DO == 96) {
      float2 hv[8];
      #pragma unroll
      for (int u = 0; u < 8; ++u)
        hv[u] = act ? *(const float2*)&h[(size_t)sv[u] * DO + 2 * lane]
                    : make_float2(0.f, 0.f);
      #pragma unroll
      for (int u = 0; u < 8; ++u) {
        acc.x = fmaf(wv[u], hv[u].x, acc.x);
        acc.y = fmaf(wv[u], hv[u].y, acc.y);
      }
    } else {
      float hv[8];
      #pragma unroll
      for (int u = 0; u < 8; ++u)
        hv[u] = act ? h[(size_t)sv[u] * DO + lane] : 0.f;
      #pragma unroll
      for (int u = 0; u < 8; ++u) acc.x = fmaf(wv[u], hv[u], acc.x);
    }
  }
  for (int e = CAP; e < deg; ++e) {
    int s = srt[start + e];
    float v = as_[s] + adn;
    v = v > 0.f ? v : 0.2f * v;
    float w = __expf(v - m);
    if (act) {
      if (DO == 96) {
        float2 hv = *(const float2*)&h[(size_t)s * DO + 2 * lane];
        acc.x = fmaf(w, hv.x, acc.x);
        acc.y = fmaf(w, hv.y, acc.y);
      } else {
        acc.x = fmaf(w, h[(size_t)s * DO + lane], acc.x);
      }
    }
  }

  const size_t b = (size_t)node * DO;
  if (act) {
    if (DO == 96) {
      float2 rv = *(const float2*)&xR[b + 2 * lane];
      float2 o;
      o.x = fmaxf(acc.x * inv, 0.f) + rv.x;
      o.y = fmaxf(acc.y * inv, 0.f) + rv.y;
      *(float2*)&xout[b + 2 * lane] = o;
    } else {
      xout[b + lane] = fmaxf(acc.x * inv, 0.f) + xR[b + lane];
    }
  }
}

// ---------------- launch ----------------

extern "C" void kernel_launch(void* const* d_in, const int* in_sizes, int n_in,
                              void* d_out, int out_size, void* d_ws, size_t ws_size,
                              hipStream_t stream) {
  const int N = NNODES;
  const float* x0 = (const float*)d_in[0];
  const int*   ei = (const int*)d_in[1];
  const int E = in_sizes[1] / 2;

  const float* W0 = (const float*)d_in[2];
  const float* a0s = (const float*)d_in[3];
  const float* a0d = (const float*)d_in[4];
  const float* R0 = (const float*)d_in[5];
  const float* W1 = (const float*)d_in[6];
  const float* a1s = (const float*)d_in[7];
  const float* a1d = (const float*)d_in[8];
  const float* R1 = (const float*)d_in[9];
  const float* W2 = (const float*)d_in[10];
  const float* a2s = (const float*)d_in[11];
  const float* a2d = (const float*)d_in[12];
  const float* R2 = (const float*)d_in[13];
  const float* W3 = (const float*)d_in[14];
  const float* a3s = (const float*)d_in[15];
  const float* a3d = (const float*)d_in[16];
  const float* R3 = (const float*)d_in[17];

  char* p = (char*)d_ws;
  auto alloc = [&](size_t bytes) {
    char* r = p;
    p += (bytes + 255) & ~(size_t)255;
    return r;
  };
  int*   deg    = (int*)alloc((size_t)N * 4);        // reused as cursor
  int*   offs   = (int*)alloc((size_t)(N + 1) * 4);
  int*   blksum = (int*)alloc(64 * 4);
  int*   srt    = (int*)alloc((size_t)(E + N) * 4);
  float* h      = (float*)alloc((size_t)N * 96 * 4);
  float* xR     = (float*)alloc((size_t)N * 96 * 4);
  float* asb    = (float*)alloc((size_t)N * 4);
  float* adb    = (float*)alloc((size_t)N * 4);
  float* xA     = (float*)alloc((size_t)N * 96 * 4);
  unsigned short* Wt0 = (unsigned short*)alloc((size_t)192 * 256 * 2);
  unsigned short* Wt1 = (unsigned short*)alloc((size_t)192 * 96 * 2);
  unsigned short* Wt2 = (unsigned short*)alloc((size_t)192 * 96 * 2);
  unsigned short* Wt3 = (unsigned short*)alloc((size_t)96 * 96 * 2);

  const int NB = (N + 2047) / 2048;  // 25 scan blocks

  // CSR build (dst-sorted, self-loop first in each segment)
  k_deg_init<<<(N + 255) / 256, 256, 0, stream>>>(deg, N);
  k_deg_count<<<(E + 255) / 256, 256, 0, stream>>>(ei, deg, E);
  k_scan1<<<NB, 256, 0, stream>>>(deg, offs, blksum, N);
  k_scan2<<<1, 64, 0, stream>>>(blksum, NB);
  k_scan3<<<(N + 255) / 256, 256, 0, stream>>>(offs, blksum, N);
  k_selfloop<<<(N + 255) / 256, 256, 0, stream>>>(offs, deg, srt, N);
  k_scatter<<<(E + 255) / 256, 256, 0, stream>>>(ei, offs, deg, srt, E);

  // weight convert/transpose (bf16)
  k_wt<<<(192 * 256 + 255) / 256, 256, 0, stream>>>(W0, R0, Wt0, 256, 96);
  k_wt<<<(192 * 96 + 255) / 256, 256, 0, stream>>>(W1, R1, Wt1, 96, 96);
  k_wt<<<(192 * 96 + 255) / 256, 256, 0, stream>>>(W2, R2, Wt2, 96, 96);
  k_wt<<<(96 * 96 + 255) / 256, 256, 0, stream>>>(W3, R3, Wt3, 96, 48);

  const int GB = (N + 63) / 64;

  // layer 0: K=256, DO=96
  gemm_mfma<256, 12><<<GB, 256, 0, stream>>>(x0, Wt0, a0s, a0d, h, xR, asb, adb);
  k_aggregate<96><<<(N + 3) / 4, 256, 0, stream>>>(h, xR, asb, adb, srt, offs, xA, N);

  // layer 1
  gemm_mfma<96, 12><<<GB, 256, 0, stream>>>(xA, Wt1, a1s, a1d, h, xR, asb, adb);
  k_aggregate<96><<<(N + 3) / 4, 256, 0, stream>>>(h, xR, asb, adb, srt, offs, xA, N);

  // layer 2
  gemm_mfma<96, 12><<<GB, 256, 0, stream>>>(xA, Wt2, a2s, a2d, h, xR, asb, adb);
  k_aggregate<96><<<(N + 3) / 4, 256, 0, stream>>>(h, xR, asb, adb, srt, offs, xA, N);

  // layer 3: K=96, DO=48 -> d_out
  gemm_mfma<96, 6><<<GB, 256, 0, stream>>>(xA, Wt3, a3s, a3d, h, xR, asb, adb);
  k_aggregate<48><<<(N + 3) / 4, 256, 0, stream>>>(h, xR, asb, adb, srt, offs,
                                                   (float*)d_out, N);
}

// Round 5
// 308.162 us; speedup vs baseline: 2.2061x; 1.1595x over previous
//
#include <hip/hip_runtime.h>
#include <hip/hip_bf16.h>
#include <cstdint>
#include <cstddef>

#define NNODES 50000

using s8v = __attribute__((ext_vector_type(8))) short;
using f4v = __attribute__((ext_vector_type(4))) float;

__device__ __forceinline__ unsigned short f2bf(float f) {
  union { float f; uint32_t u; } x; x.f = f;
  uint32_t r = x.u + 0x7FFF + ((x.u >> 16) & 1);  // RNE
  return (unsigned short)(r >> 16);
}
__device__ __forceinline__ float bf2f(unsigned short b) {
  union { uint32_t u; float f; } x; x.u = ((uint32_t)b) << 16;
  return x.f;
}

// ---------------- CSR build ----------------

__global__ void k_deg_init(int* __restrict__ deg, int n) {
  int i = blockIdx.x * 256 + threadIdx.x;
  if (i < n) deg[i] = 1;  // self-loop
}

__global__ void k_deg_count(const int* __restrict__ ei, int* __restrict__ deg, int E) {
  int e = blockIdx.x * 256 + threadIdx.x;
  if (e < E) atomicAdd(&deg[ei[E + e]], 1);
}

__global__ __launch_bounds__(256) void k_scan1(const int* __restrict__ deg,
                                               int* __restrict__ offs,
                                               int* __restrict__ blksum, int n) {
  __shared__ int part[256];
  const int tid = threadIdx.x;
  const int base = blockIdx.x * 2048 + tid * 8;
  int v[8]; int s = 0;
  #pragma unroll
  for (int u = 0; u < 8; ++u) {
    int i = base + u;
    v[u] = (i < n) ? deg[i] : 0;
    s += v[u];
  }
  part[tid] = s;
  __syncthreads();
  for (int off = 1; off < 256; off <<= 1) {
    int t = (tid >= off) ? part[tid - off] : 0;
    __syncthreads();
    part[tid] += t;
    __syncthreads();
  }
  int run = (tid == 0) ? 0 : part[tid - 1];
  #pragma unroll
  for (int u = 0; u < 8; ++u) {
    int i = base + u;
    run += v[u];
    if (i < n) offs[i + 1] = run;
  }
  if (tid == 255) blksum[blockIdx.x] = part[255];
}

__global__ void k_scan2(int* __restrict__ blksum, int nb) {
  int t = threadIdx.x;
  int v = (t < nb) ? blksum[t] : 0;
  for (int off = 1; off < 64; off <<= 1) {
    int o = __shfl_up(v, off, 64);
    if (t >= off) v += o;
  }
  if (t < nb) blksum[t] = v;
}

__global__ void k_scan3(int* __restrict__ offs, const int* __restrict__ blksum, int n) {
  int i = blockIdx.x * 256 + threadIdx.x;
  if (i < n) {
    int b = i >> 11;
    if (b > 0) offs[i + 1] += blksum[b - 1];
  }
  if (i == 0) offs[0] = 0;
}

__global__ void k_selfloop(const int* __restrict__ offs, int* __restrict__ cursor,
                           int* __restrict__ srt, int n) {
  int i = blockIdx.x * 256 + threadIdx.x;
  if (i < n) { cursor[i] = 1; srt[offs[i]] = i; }
}

__global__ void k_scatter(const int* __restrict__ ei, const int* __restrict__ offs,
                          int* __restrict__ cursor, int* __restrict__ srt, int E) {
  int e = blockIdx.x * 256 + threadIdx.x;
  if (e < E) {
    int s = ei[e], d = ei[E + e];
    int pos = offs[d] + atomicAdd(&cursor[d], 1);
    srt[pos] = s;
  }
}

// ---------------- weight pre-transpose + bf16 convert (all 4 layers) ----------------

__global__ void k_wt_all(const float* __restrict__ W0, const float* __restrict__ R0,
                         const float* __restrict__ W1, const float* __restrict__ R1,
                         const float* __restrict__ W2, const float* __restrict__ R2,
                         const float* __restrict__ W3, const float* __restrict__ R3,
                         unsigned short* __restrict__ Wt0, unsigned short* __restrict__ Wt1,
                         unsigned short* __restrict__ Wt2, unsigned short* __restrict__ Wt3) {
  int idx = blockIdx.x * 256 + threadIdx.x;
  const float *W, *R; unsigned short* Wt; int K, DO, l;
  if (idx < 49152)      { l = idx;          W = W0; R = R0; Wt = Wt0; K = 256; DO = 96; }
  else if (idx < 67584) { l = idx - 49152;  W = W1; R = R1; Wt = Wt1; K = 96;  DO = 96; }
  else if (idx < 86016) { l = idx - 67584;  W = W2; R = R2; Wt = Wt2; K = 96;  DO = 96; }
  else if (idx < 95232) { l = idx - 86016;  W = W3; R = R3; Wt = Wt3; K = 96;  DO = 48; }
  else return;
  int n = l / K, k = l % K;
  float v = (n < DO) ? W[(size_t)k * DO + n] : R[(size_t)k * DO + (n - DO)];
  Wt[l] = f2bf(v);
}

// ---------------- MFMA GEMM + fused alpha dots; h output in bf16 ----------------

template<int KDIM, int NT>   // NT = DOW/16
__global__ __launch_bounds__(256) void gemm_mfma(
    const float* __restrict__ x, const unsigned short* __restrict__ Wt,
    const float* __restrict__ a_s, const float* __restrict__ a_d,
    unsigned short* __restrict__ hb, float* __restrict__ xR,
    float* __restrict__ asb, float* __restrict__ adb) {
  constexpr int DOW = NT * 16;
  constexpr int DO  = DOW / 2;
  constexpr int NH  = NT / 2;
  constexpr int BM  = 64;
  constexpr int AP  = 40;
  __shared__ __align__(16) unsigned short Al[BM * AP];
  __shared__ __align__(16) unsigned short Bl[DOW * AP];

  const int tid  = threadIdx.x;
  const int wave = tid >> 6;
  const int lane = tid & 63;
  const int row0 = blockIdx.x * BM;

  f4v acc[NT];
  #pragma unroll
  for (int t = 0; t < NT; ++t) acc[t] = (f4v)(0.f);

  const int fr = lane & 15;
  const int fq = lane >> 4;

  for (int k0 = 0; k0 < KDIM; k0 += 32) {
    __syncthreads();
    {
      int r = tid >> 2, ko = (tid & 3) * 8;
      int gr = row0 + r;
      s8v out;
      if (gr < NNODES) {
        const float* xp = &x[(size_t)gr * KDIM + k0 + ko];
        float4 v0 = *(const float4*)(xp);
        float4 v1 = *(const float4*)(xp + 4);
        out[0] = (short)f2bf(v0.x); out[1] = (short)f2bf(v0.y);
        out[2] = (short)f2bf(v0.z); out[3] = (short)f2bf(v0.w);
        out[4] = (short)f2bf(v1.x); out[5] = (short)f2bf(v1.y);
        out[6] = (short)f2bf(v1.z); out[7] = (short)f2bf(v1.w);
      } else {
        out = (s8v)(0);
      }
      *(s8v*)&Al[r * AP + ko] = out;
    }
    for (int s = tid; s < DOW * 4; s += 256) {
      int n = s >> 2, ko = (s & 3) * 8;
      s8v v = *(const s8v*)&Wt[(size_t)n * KDIM + k0 + ko];
      *(s8v*)&Bl[n * AP + ko] = v;
    }
    __syncthreads();

    s8v a = *(const s8v*)&Al[(wave * 16 + fr) * AP + fq * 8];
    #pragma unroll
    for (int t = 0; t < NT; ++t) {
      s8v b = *(const s8v*)&Bl[(t * 16 + fr) * AP + fq * 8];
      acc[t] = __builtin_amdgcn_mfma_f32_16x16x32_bf16(a, b, acc[t], 0, 0, 0);
    }
  }

  // C write: D col = lane&15, row = (lane>>4)*4 + reg
  #pragma unroll
  for (int t = 0; t < NT; ++t) {
    int gcol = t * 16 + fr;
    #pragma unroll
    for (int r = 0; r < 4; ++r) {
      int grow = row0 + wave * 16 + fq * 4 + r;
      if (grow >= NNODES) continue;
      if (t < NH) hb[(size_t)grow * DO + gcol] = f2bf(acc[t][r]);
      else        xR[(size_t)grow * DO + (gcol - DO)] = acc[t][r];
    }
  }

  // fused alpha dots over h columns (fp32 accumulators)
  float avs[NH], avd[NH];
  #pragma unroll
  for (int t = 0; t < NH; ++t) {
    avs[t] = a_s[t * 16 + fr];
    avd[t] = a_d[t * 16 + fr];
  }
  #pragma unroll
  for (int r = 0; r < 4; ++r) {
    float ps = 0.f, pd = 0.f;
    #pragma unroll
    for (int t = 0; t < NH; ++t) {
      ps = fmaf(acc[t][r], avs[t], ps);
      pd = fmaf(acc[t][r], avd[t], pd);
    }
    #pragma unroll
    for (int off = 1; off < 16; off <<= 1) {
      ps += __shfl_xor(ps, off, 64);
      pd += __shfl_xor(pd, off, 64);
    }
    int grow = row0 + wave * 16 + fq * 4 + r;
    if (fr == 0 && grow < NNODES) { asb[grow] = ps; adb[grow] = pd; }
  }
}

// ---------------- fused softmax + aggregate + relu + residual (bf16 h) ----------------

template<int DO>
__global__ __launch_bounds__(256) void k_aggregate(
    const unsigned short* __restrict__ hb, const float* __restrict__ xR,
    const float* __restrict__ as_, const float* __restrict__ ad_,
    const int* __restrict__ srt, const int* __restrict__ offs,
    float* __restrict__ xout, int n) {
  constexpr int CAP = 256;
  __shared__ float wbuf[4][CAP];
  __shared__ int   sbuf[4][CAP];
  const int lane = threadIdx.x & 63;
  const int wid  = threadIdx.x >> 6;
  const int node = blockIdx.x * 4 + wid;
  if (node >= n) return;
  const int start = offs[node];
  const int deg   = offs[node + 1] - start;
  const float adn = ad_[node];

  float m = -INFINITY;
  for (int idx = lane; idx < deg; idx += 64) {
    int s = srt[start + idx];
    float v = as_[s] + adn;
    v = v > 0.f ? v : 0.2f * v;
    if (idx < CAP) { wbuf[wid][idx] = v; sbuf[wid][idx] = s; }
    m = fmaxf(m, v);
  }
  #pragma unroll
  for (int off = 32; off; off >>= 1) m = fmaxf(m, __shfl_xor(m, off, 64));

  float ssum = 0.f;
  for (int idx = lane; idx < deg; idx += 64) {
    float v;
    if (idx < CAP) v = wbuf[wid][idx];
    else {
      int s = srt[start + idx];
      v = as_[s] + adn;
      v = v > 0.f ? v : 0.2f * v;
    }
    float w = __expf(v - m);
    if (idx < CAP) wbuf[wid][idx] = w;
    ssum += w;
  }
  #pragma unroll
  for (int off = 32; off; off >>= 1) ssum += __shfl_xor(ssum, off, 64);
  const float inv = 1.f / ssum;

  // phase 3: feature-parallel gather from bf16 h.
  // DO=96: lane<48 owns 2 features (one dword). DO=48: lane<24 owns 2 features.
  constexpr int NL = DO / 2;         // active lanes
  const bool act = lane < NL;
  const int dcap = min(deg, CAP);
  float2 acc = make_float2(0.f, 0.f);
  for (int base = 0; base < dcap; base += 8) {
    float wv[8]; int sv[8];
    #pragma unroll
    for (int u = 0; u < 8; ++u) {
      int e = base + u;
      bool ok = e < dcap;
      sv[u] = sbuf[wid][ok ? e : 0];
      wv[u] = ok ? wbuf[wid][e] : 0.f;
    }
    uint32_t hv[8];
    #pragma unroll
    for (int u = 0; u < 8; ++u)
      hv[u] = act ? *(const uint32_t*)&hb[(size_t)sv[u] * DO + 2 * lane] : 0u;
    #pragma unroll
    for (int u = 0; u < 8; ++u) {
      acc.x = fmaf(wv[u], bf2f((unsigned short)(hv[u] & 0xFFFF)), acc.x);
      acc.y = fmaf(wv[u], bf2f((unsigned short)(hv[u] >> 16)), acc.y);
    }
  }
  for (int e = CAP; e < deg; ++e) {
    int s = srt[start + e];
    float v = as_[s] + adn;
    v = v > 0.f ? v : 0.2f * v;
    float w = __expf(v - m);
    if (act) {
      uint32_t hv = *(const uint32_t*)&hb[(size_t)s * DO + 2 * lane];
      acc.x = fmaf(w, bf2f((unsigned short)(hv & 0xFFFF)), acc.x);
      acc.y = fmaf(w, bf2f((unsigned short)(hv >> 16)), acc.y);
    }
  }

  const size_t b = (size_t)node * DO;
  if (act) {
    float2 rv = *(const float2*)&xR[b + 2 * lane];
    float2 o;
    o.x = fmaxf(acc.x * inv, 0.f) + rv.x;
    o.y = fmaxf(acc.y * inv, 0.f) + rv.y;
    *(float2*)&xout[b + 2 * lane] = o;
  }
}

// ---------------- launch ----------------

extern "C" void kernel_launch(void* const* d_in, const int* in_sizes, int n_in,
                              void* d_out, int out_size, void* d_ws, size_t ws_size,
                              hipStream_t stream) {
  const int N = NNODES;
  const float* x0 = (const float*)d_in[0];
  const int*   ei = (const int*)d_in[1];
  const int E = in_sizes[1] / 2;

  const float* W0 = (const float*)d_in[2];
  const float* a0s = (const float*)d_in[3];
  const float* a0d = (const float*)d_in[4];
  const float* R0 = (const float*)d_in[5];
  const float* W1 = (const float*)d_in[6];
  const float* a1s = (const float*)d_in[7];
  const float* a1d = (const float*)d_in[8];
  const float* R1 = (const float*)d_in[9];
  const float* W2 = (const float*)d_in[10];
  const float* a2s = (const float*)d_in[11];
  const float* a2d = (const float*)d_in[12];
  const float* R2 = (const float*)d_in[13];
  const float* W3 = (const float*)d_in[14];
  const float* a3s = (const float*)d_in[15];
  const float* a3d = (const float*)d_in[16];
  const float* R3 = (const float*)d_in[17];

  char* p = (char*)d_ws;
  auto alloc = [&](size_t bytes) {
    char* r = p;
    p += (bytes + 255) & ~(size_t)255;
    return r;
  };
  int*   deg    = (int*)alloc((size_t)N * 4);        // reused as cursor
  int*   offs   = (int*)alloc((size_t)(N + 1) * 4);
  int*   blksum = (int*)alloc(64 * 4);
  int*   srt    = (int*)alloc((size_t)(E + N) * 4);
  unsigned short* hb = (unsigned short*)alloc((size_t)N * 96 * 2);
  float* xR     = (float*)alloc((size_t)N * 96 * 4);
  float* asb    = (float*)alloc((size_t)N * 4);
  float* adb    = (float*)alloc((size_t)N * 4);
  float* xA     = (float*)alloc((size_t)N * 96 * 4);
  unsigned short* Wt0 = (unsigned short*)alloc((size_t)192 * 256 * 2);
  unsigned short* Wt1 = (unsigned short*)alloc((size_t)192 * 96 * 2);
  unsigned short* Wt2 = (unsigned short*)alloc((size_t)192 * 96 * 2);
  unsigned short* Wt3 = (unsigned short*)alloc((size_t)96 * 96 * 2);

  const int NB = (N + 2047) / 2048;

  k_deg_init<<<(N + 255) / 256, 256, 0, stream>>>(deg, N);
  k_deg_count<<<(E + 255) / 256, 256, 0, stream>>>(ei, deg, E);
  k_scan1<<<NB, 256, 0, stream>>>(deg, offs, blksum, N);
  k_scan2<<<1, 64, 0, stream>>>(blksum, NB);
  k_scan3<<<(N + 255) / 256, 256, 0, stream>>>(offs, blksum, N);
  k_selfloop<<<(N + 255) / 256, 256, 0, stream>>>(offs, deg, srt, N);
  k_scatter<<<(E + 255) / 256, 256, 0, stream>>>(ei, offs, deg, srt, E);

  k_wt_all<<<(95232 + 255) / 256, 256, 0, stream>>>(W0, R0, W1, R1, W2, R2, W3, R3,
                                                    Wt0, Wt1, Wt2, Wt3);

  const int GB = (N + 63) / 64;

  // layer 0: K=256, DO=96
  gemm_mfma<256, 12><<<GB, 256, 0, stream>>>(x0, Wt0, a0s, a0d, hb, xR, asb, adb);
  k_aggregate<96><<<(N + 3) / 4, 256, 0, stream>>>(hb, xR, asb, adb, srt, offs, xA, N);

  // layer 1
  gemm_mfma<96, 12><<<GB, 256, 0, stream>>>(xA, Wt1, a1s, a1d, hb, xR, asb, adb);
  k_aggregate<96><<<(N + 3) / 4, 256, 0, stream>>>(hb, xR, asb, adb, srt, offs, xA, N);

  // layer 2
  gemm_mfma<96, 12><<<GB, 256, 0, stream>>>(xA, Wt2, a2s, a2d, hb, xR, asb, adb);
  k_aggregate<96><<<(N + 3) / 4, 256, 0, stream>>>(hb, xR, asb, adb, srt, offs, xA, N);

  // layer 3: K=96, DO=48 -> d_out
  gemm_mfma<96, 6><<<GB, 256, 0, stream>>>(xA, Wt3, a3s, a3d, hb, xR, asb, adb);
  k_aggregate<48><<<(N + 3) / 4, 256, 0, stream>>>(hb, xR, asb, adb, srt, offs,
                                                   (float*)d_out, N);
}